// Round 1
// baseline (557.534 us; speedup 1.0000x reference)
//
#include <hip/hip_runtime.h>

#define BSZ 128
#define NN  4000
#define DD  128
#define NB  10
#define SEQ 400
#define C1N 32
#define C2N 32

// w1t[(k*32 + c1)*128 + d] = conv1_w[c1*1280 + d*10 + k]   (layout [k][c1][d])
__global__ void pscn_prep(const float* __restrict__ w1, float* __restrict__ w1t) {
    int t = blockIdx.x * 256 + threadIdx.x;
    if (t >= C1N * DD * NB) return;
    int d  = t & 127;
    int c1 = (t >> 7) & 31;
    int k  = t >> 12;
    w1t[t] = w1[c1 * (DD * NB) + d * NB + k];
}

__global__ void pscn_init_out(const float* __restrict__ fc_b, float* __restrict__ out) {
    int t = threadIdx.x;
    if (t < BSZ) out[t] = fc_b[0];
}

__global__ __launch_bounds__(256, 3) void pscn_main(
    const int*   __restrict__ recep,
    const float* __restrict__ node_feat,
    const float* __restrict__ w1t,
    const float* __restrict__ b1,
    const float* __restrict__ w2,
    const float* __restrict__ cb2,
    const float* __restrict__ fcw,
    float*       __restrict__ out)
{
    // part[wave][c1][s_l]: lane-consecutive stores -> conflict-free
    __shared__ float part[4][32][64];
    __shared__ float y1s[32][64];
    __shared__ float w2s[32 * 32];      // w2s[c1*32 + c2] = conv2_w[c2][c1]
    __shared__ float contrib[64];

    const int tid  = threadIdx.x;
    const int lane = tid & 63;
    const int wv   = tid >> 6;
    // d-chunk id: wave-uniform by construction; force into SGPR so conv1
    // weight addresses are uniform -> s_load + v_fmac(v,s,v)
    const int dq = __builtin_amdgcn_readfirstlane(wv);
    const int dbase = dq * 32;

    // stage conv2 weights transposed
    for (int i = tid; i < 1024; i += 256) {
        int c1 = i >> 5, c2 = i & 31;
        w2s[c1 * 32 + c2] = w2[c2 * 32 + c1];
    }

    const int sid = blockIdx.x * 64 + lane;     // global sequence position
    const int b   = sid / SEQ;
    const int sp  = sid - b * SEQ;

    float acc[32];
#pragma unroll
    for (int c = 0; c < 32; ++c) acc[c] = 0.f;

    for (int k = 0; k < NB; ++k) {
        const int idx = recep[b * NN + sp * NB + k];
        const float* row = node_feat + (long)(b * NN + idx) * DD + dbase;
        float4 a[8];
#pragma unroll
        for (int i = 0; i < 8; ++i) a[i] = ((const float4*)row)[i];
        const float* wk = w1t + (k * 32) * 128 + dbase;
#pragma unroll
        for (int c = 0; c < 32; ++c) {
            const float* wc = wk + c * 128;   // uniform address -> scalar loads
            float s = 0.f;
#pragma unroll
            for (int i = 0; i < 8; ++i) {
                float4 w4 = ((const float4*)wc)[i];
                s += a[i].x * w4.x + a[i].y * w4.y + a[i].z * w4.z + a[i].w * w4.w;
            }
            acc[c] += s;
        }
    }

#pragma unroll
    for (int c = 0; c < 32; ++c) part[wv][c][lane] = acc[c];
    __syncthreads();

    // cross-wave (d-chunk) reduce + bias + relu -> y1s[c1][s_l]
#pragma unroll
    for (int o = 0; o < 8; ++o) {
        int c1 = o * 4 + wv;
        float v = part[0][c1][lane] + part[1][c1][lane]
                + part[2][c1][lane] + part[3][c1][lane];
        v += b1[c1];
        y1s[c1][lane] = fmaxf(v, 0.f);
    }
    __syncthreads();

    // conv2 (1x1) + relu + fc partial dot: thread = (s_l, c2-octet q)
    {
        const int s_l  = tid >> 2;
        const int q    = tid & 3;
        const int sid2 = blockIdx.x * 64 + s_l;
        const int bb   = sid2 / SEQ;
        const int sp2  = sid2 - bb * SEQ;
        float val = 0.f;
#pragma unroll
        for (int j = 0; j < 8; ++j) {
            const int c2 = q * 8 + j;
            float y2 = cb2[c2];
#pragma unroll
            for (int c1 = 0; c1 < 32; ++c1)
                y2 += y1s[c1][s_l] * w2s[c1 * 32 + c2];
            y2 = fmaxf(y2, 0.f);
            val += y2 * fcw[c2 * SEQ + sp2];
        }
        val += __shfl_xor(val, 1);
        val += __shfl_xor(val, 2);
        if (q == 0) contrib[s_l] = val;
    }
    __syncthreads();

    // block-level reduce (<=2 distinct graphs per block), then atomicAdd
    if (wv == 0) {
        float v = contrib[lane];
        const int bl     = (blockIdx.x * 64 + lane) / SEQ;
        const int bfirst = (blockIdx.x * 64) / SEQ;
        const int blast  = (blockIdx.x * 64 + 63) / SEQ;
        for (int tb = bfirst; tb <= blast; ++tb) {
            float r = (bl == tb) ? v : 0.f;
#pragma unroll
            for (int off = 1; off < 64; off <<= 1) r += __shfl_xor(r, off);
            if (lane == 0) atomicAdd(&out[tb], r);
        }
    }
}

extern "C" void kernel_launch(void* const* d_in, const int* in_sizes, int n_in,
                              void* d_out, int out_size, void* d_ws, size_t ws_size,
                              hipStream_t stream) {
    const int*   recep = (const int*)  d_in[0];
    const float* nfeat = (const float*)d_in[1];
    const float* w1    = (const float*)d_in[2];
    const float* b1    = (const float*)d_in[3];
    const float* w2    = (const float*)d_in[4];
    const float* cb2   = (const float*)d_in[5];
    const float* fcw   = (const float*)d_in[6];
    const float* fcb   = (const float*)d_in[7];
    float* outp = (float*)d_out;
    float* w1t  = (float*)d_ws;          // 40960 floats = 160 KB

    pscn_prep<<<(C1N * DD * NB + 255) / 256, 256, 0, stream>>>(w1, w1t);
    pscn_init_out<<<1, 128, 0, stream>>>(fcb, outp);
    pscn_main<<<(BSZ * SEQ) / 64, 256, 0, stream>>>(
        recep, nfeat, w1t, b1, w2, cb2, fcw, outp);
}

// Round 2
// 462.538 us; speedup vs baseline: 1.2054x; 1.2054x over previous
//
#include <hip/hip_runtime.h>

#define BSZ 128
#define NN  4000
#define DD  128
#define NB  10
#define SEQ 400
#define C1N 32
#define C2N 32

// w1t[(k*32 + c1)*128 + d] = conv1_w[c1*1280 + d*10 + k]   (layout [k][c1][d])
__global__ void pscn_prep(const float* __restrict__ w1, float* __restrict__ w1t) {
    int t = blockIdx.x * 256 + threadIdx.x;
    if (t >= C1N * DD * NB) return;
    int d  = t & 127;
    int c1 = (t >> 7) & 31;
    int k  = t >> 12;
    w1t[t] = w1[c1 * (DD * NB) + d * NB + k];
}

__global__ void pscn_init_out(const float* __restrict__ fc_b, float* __restrict__ out) {
    if (threadIdx.x < BSZ) out[threadIdx.x] = fc_b[0];
}

// Block = 512 thr = 8 waves: wave w -> (dq = w&3 : 32-wide d-chunk, kh = w>>2 : 5-neighbor half)
// Lanes = 64 sequence positions. Grid = 800 blocks -> 24 waves/CU at 3 blocks/CU.
__global__ __launch_bounds__(512, 6) void pscn_main(
    const int*   __restrict__ recep,
    const float* __restrict__ node_feat,
    const float* __restrict__ w1t,
    const float* __restrict__ b1,
    const float* __restrict__ w2,
    const float* __restrict__ cb2,
    const float* __restrict__ fcw,
    float*       __restrict__ out)
{
    __shared__ float part[4][32][64];   // 32 KB  (per-dq partial sums)
    __shared__ float y1s[32][64];       // 8 KB   (conv1 output)
    __shared__ float w2s[32 * 32];      // 4 KB   w2s[c1*32+c2] = conv2_w[c2][c1]
    __shared__ float contrib[64];

    const int tid  = threadIdx.x;
    const int lane = tid & 63;
    const int wv   = tid >> 6;                                   // 0..7
    const int dq   = __builtin_amdgcn_readfirstlane(wv & 3);     // wave-uniform -> SGPR
    const int kh   = __builtin_amdgcn_readfirstlane(wv >> 2);
    const int dbase = dq * 32;

    for (int i = tid; i < 1024; i += 512) {
        int c1 = i >> 5, c2 = i & 31;
        w2s[c1 * 32 + c2] = w2[c2 * 32 + c1];
    }

    const int sid = blockIdx.x * 64 + lane;     // global sequence position
    const int b   = sid / SEQ;
    const int sp  = sid - b * SEQ;

    // hoist all 5 neighbor indices (contiguous ints) -> independent early loads
    const int* rrow = recep + b * NN + sp * NB + kh * 5;
    int idxs[5];
#pragma unroll
    for (int kk = 0; kk < 5; ++kk) idxs[kk] = rrow[kk];

    float acc[32];
#pragma unroll
    for (int c = 0; c < 32; ++c) acc[c] = 0.f;

    const long gbase = (long)b * NN * DD;
#pragma unroll
    for (int kk = 0; kk < 5; ++kk) {
        const float* row = node_feat + gbase + (long)idxs[kk] * DD + dbase;
        float4 a[8];
#pragma unroll
        for (int i = 0; i < 8; ++i) a[i] = ((const float4*)row)[i];
        const int k = kh * 5 + kk;
        const float* wk = w1t + (k * 32) * 128 + dbase;   // wave-uniform -> s_load
#pragma unroll
        for (int c = 0; c < 32; ++c) {
            const float* wc = wk + c * 128;
            float s0 = 0.f;
#pragma unroll
            for (int i = 0; i < 8; ++i) {
                float4 w4 = ((const float4*)wc)[i];
                s0 += a[i].x * w4.x + a[i].y * w4.y + a[i].z * w4.z + a[i].w * w4.w;
            }
            acc[c] += s0;
        }
    }

    // combine kh halves into part[dq], then reduce over dq
    if (kh == 1) {
#pragma unroll
        for (int c = 0; c < 32; ++c) part[dq][c][lane] = acc[c];
    }
    __syncthreads();
    if (kh == 0) {
#pragma unroll
        for (int c = 0; c < 32; ++c) part[dq][c][lane] += acc[c];
    }
    __syncthreads();

#pragma unroll
    for (int j = 0; j < 4; ++j) {
        const int c1 = wv * 4 + j;
        float v = part[0][c1][lane] + part[1][c1][lane]
                + part[2][c1][lane] + part[3][c1][lane] + b1[c1];
        y1s[c1][lane] = fmaxf(v, 0.f);
    }
    __syncthreads();

    // conv2 (1x1) + relu + fc partial dot: thread = (s_l = tid>>3, oct = tid&7), 4 c2 each
    {
        const int s_l  = tid >> 3;
        const int oct  = tid & 7;
        const int sid2 = blockIdx.x * 64 + s_l;
        const int bb   = sid2 / SEQ;
        const int sp2  = sid2 - bb * SEQ;
        float val = 0.f;
#pragma unroll
        for (int j = 0; j < 4; ++j) {
            const int c2 = oct * 4 + j;
            float y2 = cb2[c2];
#pragma unroll
            for (int c1 = 0; c1 < 32; ++c1)
                y2 += y1s[c1][s_l] * w2s[c1 * 32 + c2];
            y2 = fmaxf(y2, 0.f);
            val += y2 * fcw[c2 * SEQ + sp2];
        }
        val += __shfl_xor(val, 1);
        val += __shfl_xor(val, 2);
        val += __shfl_xor(val, 4);
        if (oct == 0) contrib[s_l] = val;
    }
    __syncthreads();

    // block-level reduce (<=2 distinct graphs per block), then atomicAdd
    if (wv == 0) {
        float v = contrib[lane];
        const int bl     = (blockIdx.x * 64 + lane) / SEQ;
        const int bfirst = (blockIdx.x * 64) / SEQ;
        const int blast  = (blockIdx.x * 64 + 63) / SEQ;
        for (int tb = bfirst; tb <= blast; ++tb) {
            float r = (bl == tb) ? v : 0.f;
#pragma unroll
            for (int off = 1; off < 64; off <<= 1) r += __shfl_xor(r, off);
            if (lane == 0) atomicAdd(&out[tb], r);
        }
    }
}

extern "C" void kernel_launch(void* const* d_in, const int* in_sizes, int n_in,
                              void* d_out, int out_size, void* d_ws, size_t ws_size,
                              hipStream_t stream) {
    const int*   recep = (const int*)  d_in[0];
    const float* nfeat = (const float*)d_in[1];
    const float* w1    = (const float*)d_in[2];
    const float* b1    = (const float*)d_in[3];
    const float* w2    = (const float*)d_in[4];
    const float* cb2   = (const float*)d_in[5];
    const float* fcw   = (const float*)d_in[6];
    const float* fcb   = (const float*)d_in[7];
    float* outp = (float*)d_out;
    float* w1t  = (float*)d_ws;          // 40960 floats = 160 KB

    pscn_prep<<<(C1N * DD * NB + 255) / 256, 256, 0, stream>>>(w1, w1t);
    pscn_init_out<<<1, 128, 0, stream>>>(fcb, outp);
    pscn_main<<<(BSZ * SEQ) / 64, 512, 0, stream>>>(
        recep, nfeat, w1t, b1, w2, cb2, fcw, outp);
}

// Round 3
// 377.529 us; speedup vs baseline: 1.4768x; 1.2252x over previous
//
#include <hip/hip_runtime.h>
#include <hip/hip_bf16.h>

#define BSZ 128
#define NN  4000
#define DD  128
#define NB  10
#define SEQ 400

typedef __attribute__((ext_vector_type(8)))  short short8;
typedef __attribute__((ext_vector_type(16))) float f32x16;

// ---- prep: swizzle conv1_w into exact B-fragment order for v_mfma_f32_32x32x16_bf16
// Bfrag[ks][t][lane][j], K-assignment per wave ks (K=320 each):
//   t 0-7   -> neighbor 2ks,   d = t*16 + kin
//   t 8-15  -> neighbor 2ks+1, d = (t-8)*16 + kin
//   t 16-19 -> neighbor 8+(ks>>1), d = (ks&1)*64 + (t-16)*16 + kin
// kin = (lane>>5)*8 + j  (B: n=lane&31, k=kin)
__global__ void pscn_prep(const float* __restrict__ w1, unsigned short* __restrict__ bf) {
    int id = blockIdx.x * 256 + threadIdx.x;
    if (id >= 40960) return;
    int j   = id & 7;
    int l   = (id >> 3) & 63;
    int rem = id >> 9;            // ks*20 + t
    int t   = rem % 20;
    int ks  = rem / 20;
    int kin = ((l >> 5) << 3) + j;
    int kk, d;
    if (t < 8)       { kk = 2 * ks;         d = t * 16 + kin; }
    else if (t < 16) { kk = 2 * ks + 1;     d = (t - 8) * 16 + kin; }
    else             { kk = 8 + (ks >> 1);  d = (ks & 1) * 64 + (t - 16) * 16 + kin; }
    int c1 = l & 31;
    float v = w1[c1 * (DD * NB) + d * NB + kk];
    union { __hip_bfloat16 h; unsigned short u; } cv;
    cv.h = __float2bfloat16(v);
    bf[id] = cv.u;
}

__global__ void pscn_init_out(const float* __restrict__ fc_b, float* __restrict__ out) {
    if (threadIdx.x < BSZ) out[threadIdx.x] = fc_b[0];
}

__device__ inline short8 cvt8(float4 lo, float4 hi) {
    union { __hip_bfloat162 h[4]; short8 s; } u;
    u.h[0] = __float22bfloat162_rn(make_float2(lo.x, lo.y));
    u.h[1] = __float22bfloat162_rn(make_float2(lo.z, lo.w));
    u.h[2] = __float22bfloat162_rn(make_float2(hi.x, hi.y));
    u.h[3] = __float22bfloat162_rn(make_float2(hi.z, hi.w));
    return u.s;
}

// block = 256 thr = 4 waves = 4-way K-split; block covers 32 positions; grid = 1600
__global__ __launch_bounds__(256, 5) void pscn_main(
    const int*   __restrict__ recep,
    const float* __restrict__ nf,
    const short8* __restrict__ bfrag,
    const float* __restrict__ b1,
    const float* __restrict__ w2,
    const float* __restrict__ cb2,
    const float* __restrict__ fcw,
    float*       __restrict__ out)
{
    __shared__ float cred[3][32][33];   // K-split partials, bank = (p+m)%32 -> <=2-way
    __shared__ float y1s[32][33];       // [c1][pos]
    __shared__ float w2s[1024];         // w2s[c1*32+c2]
    __shared__ float contrib[32];

    const int tid  = threadIdx.x;
    const int lane = tid & 63;
    const int wv   = __builtin_amdgcn_readfirstlane(tid >> 6);
    const int ks   = wv;                // K-split id 0..3
    const int m    = lane & 31;         // position-in-tile (MFMA A: m=lane&31)
    const int half = lane >> 5;         // k-half      (MFMA A: k=half*8+j)

    for (int i = tid; i < 1024; i += 256) {
        int c1 = i >> 5, c2 = i & 31;
        w2s[c1 * 32 + c2] = w2[c2 * 32 + c1];
    }

    const int sid = blockIdx.x * 32 + m;
    const int b   = sid / SEQ;
    const int sp  = sid - b * SEQ;

    const int* rr = recep + b * NN + sp * NB;
    const int idxA = rr[2 * ks];
    const int idxB = rr[2 * ks + 1];
    const int idxC = rr[8 + (ks >> 1)];

    const float* rp[3];
    rp[0] = nf + ((size_t)b * NN + idxA) * DD + half * 8;
    rp[1] = nf + ((size_t)b * NN + idxB) * DD + half * 8;
    rp[2] = nf + ((size_t)b * NN + idxC) * DD + (ks & 1) * 64 + half * 8;

    f32x16 C;
#pragma unroll
    for (int i = 0; i < 16; ++i) C[i] = 0.f;

    const short8* bp = bfrag + ks * 20 * 64 + lane;

    float4 A[2][2][2];
    short8 Bf[2][2];
#pragma unroll
    for (int tt = 0; tt < 2; ++tt) {
        const float* p = rp[0] + tt * 16;
        A[0][tt][0] = ((const float4*)p)[0];
        A[0][tt][1] = ((const float4*)p)[1];
        Bf[0][tt]   = bp[tt * 64];
    }
#pragma unroll
    for (int g = 0; g < 10; ++g) {
        const int cur = g & 1, nxt = cur ^ 1;
        if (g < 9) {
#pragma unroll
            for (int tt = 0; tt < 2; ++tt) {
                const int t = (g + 1) * 2 + tt;           // compile-time
                const float* p = rp[t >> 3] + (t & 7) * 16;
                A[nxt][tt][0] = ((const float4*)p)[0];
                A[nxt][tt][1] = ((const float4*)p)[1];
                Bf[nxt][tt]   = bp[t * 64];
            }
        }
#pragma unroll
        for (int tt = 0; tt < 2; ++tt) {
            short8 a = cvt8(A[cur][tt][0], A[cur][tt][1]);
            C = __builtin_amdgcn_mfma_f32_32x32x16_bf16(a, Bf[cur][tt], C, 0, 0, 0);
        }
    }

    // reduce K-split partials; C/D: col(c1)=lane&31, row(p)=(r&3)+8*(r>>2)+4*half
    if (ks > 0) {
#pragma unroll
        for (int r = 0; r < 16; ++r) {
            int p = (r & 3) + 8 * (r >> 2) + 4 * half;
            cred[ks - 1][p][m] = C[r];
        }
    }
    __syncthreads();
    if (ks == 0) {
        float bv = b1[m];
#pragma unroll
        for (int r = 0; r < 16; ++r) {
            int p = (r & 3) + 8 * (r >> 2) + 4 * half;
            float v = C[r] + cred[0][p][m] + cred[1][p][m] + cred[2][p][m] + bv;
            y1s[m][p] = fmaxf(v, 0.f);
        }
    }
    __syncthreads();

    // conv2 (1x1) + relu + fc partial: thread = (s_l = tid>>3, oc = tid&7), 4 c2 each
    {
        const int s_l  = tid >> 3;
        const int oc   = tid & 7;
        const int sid2 = blockIdx.x * 32 + s_l;
        const int bb   = sid2 / SEQ;
        const int sp2  = sid2 - bb * SEQ;
        float val = 0.f;
#pragma unroll
        for (int j = 0; j < 4; ++j) {
            const int c2 = oc * 4 + j;
            float y2 = cb2[c2];
#pragma unroll
            for (int c1 = 0; c1 < 32; ++c1)
                y2 += y1s[c1][s_l] * w2s[c1 * 32 + c2];
            y2 = fmaxf(y2, 0.f);
            val += y2 * fcw[c2 * SEQ + sp2];
        }
        val += __shfl_xor(val, 1);
        val += __shfl_xor(val, 2);
        val += __shfl_xor(val, 4);
        if (oc == 0) contrib[s_l] = val;
    }
    __syncthreads();

    // block reduce (<=2 distinct graphs per 32-pos block) + atomicAdd
    if (wv == 0) {
        float v = (lane < 32) ? contrib[lane] : 0.f;
        const int bl     = (blockIdx.x * 32 + (lane & 31)) / SEQ;
        const int bfirst = (blockIdx.x * 32) / SEQ;
        const int blast  = (blockIdx.x * 32 + 31) / SEQ;
        for (int tb = bfirst; tb <= blast; ++tb) {
            float r = (bl == tb && lane < 32) ? v : 0.f;
#pragma unroll
            for (int off = 1; off < 64; off <<= 1) r += __shfl_xor(r, off);
            if (lane == 0) atomicAdd(&out[tb], r);
        }
    }
}

extern "C" void kernel_launch(void* const* d_in, const int* in_sizes, int n_in,
                              void* d_out, int out_size, void* d_ws, size_t ws_size,
                              hipStream_t stream) {
    const int*   recep = (const int*)  d_in[0];
    const float* nfeat = (const float*)d_in[1];
    const float* w1    = (const float*)d_in[2];
    const float* b1    = (const float*)d_in[3];
    const float* w2    = (const float*)d_in[4];
    const float* cb2   = (const float*)d_in[5];
    const float* fcw   = (const float*)d_in[6];
    const float* fcb   = (const float*)d_in[7];
    float* outp = (float*)d_out;
    unsigned short* bfrag = (unsigned short*)d_ws;   // 40960 bf16 = 80 KB

    pscn_prep<<<160, 256, 0, stream>>>(w1, bfrag);
    pscn_init_out<<<1, 128, 0, stream>>>(fcb, outp);
    pscn_main<<<(BSZ * SEQ) / 32, 256, 0, stream>>>(
        recep, nfeat, (const short8*)d_ws, b1, w2, cb2, fcw, outp);
}

// Round 4
// 373.015 us; speedup vs baseline: 1.4947x; 1.0121x over previous
//
#include <hip/hip_runtime.h>
#include <hip/hip_bf16.h>

#define BSZ 128
#define NN  4000
#define DD  128
#define NB  10
#define SEQ 400

typedef __attribute__((ext_vector_type(8)))  short short8;
typedef __attribute__((ext_vector_type(16))) float f32x16;

// ---- prep: swizzle conv1_w into exact B-fragment order for v_mfma_f32_32x32x16_bf16
// Bfrag[ks][t][lane][j], K-assignment per wave ks (K=320 each):
//   t 0-7   -> neighbor 2ks,   d = t*16 + kin
//   t 8-15  -> neighbor 2ks+1, d = (t-8)*16 + kin
//   t 16-19 -> neighbor 8+(ks>>1), d = (ks&1)*64 + (t-16)*16 + kin
// kin = (lane>>5)*8 + j  (B: n=lane&31, k=kin)
__global__ void pscn_prep(const float* __restrict__ w1, unsigned short* __restrict__ bf) {
    int id = blockIdx.x * 256 + threadIdx.x;
    if (id >= 40960) return;
    int j   = id & 7;
    int l   = (id >> 3) & 63;
    int rem = id >> 9;            // ks*20 + t
    int t   = rem % 20;
    int ks  = rem / 20;
    int kin = ((l >> 5) << 3) + j;
    int kk, d;
    if (t < 8)       { kk = 2 * ks;         d = t * 16 + kin; }
    else if (t < 16) { kk = 2 * ks + 1;     d = (t - 8) * 16 + kin; }
    else             { kk = 8 + (ks >> 1);  d = (ks & 1) * 64 + (t - 16) * 16 + kin; }
    int c1 = l & 31;
    float v = w1[c1 * (DD * NB) + d * NB + kk];
    union { __hip_bfloat16 h; unsigned short u; } cv;
    cv.h = __float2bfloat16(v);
    bf[id] = cv.u;
}

__global__ void pscn_init_out(const float* __restrict__ fc_b, float* __restrict__ out) {
    if (threadIdx.x < BSZ) out[threadIdx.x] = fc_b[0];
}

__device__ inline short8 cvt8(float4 lo, float4 hi) {
    union { __hip_bfloat162 h[4]; short8 s; } u;
    u.h[0] = __float22bfloat162_rn(make_float2(lo.x, lo.y));
    u.h[1] = __float22bfloat162_rn(make_float2(lo.z, lo.w));
    u.h[2] = __float22bfloat162_rn(make_float2(hi.x, hi.y));
    u.h[3] = __float22bfloat162_rn(make_float2(hi.z, hi.w));
    return u.s;
}

// block = 256 thr = 4 waves = 4-way K-split; block covers 32 positions; grid = 1600
// launch_bounds (256,4): 128-VGPR cap -> no scratch spill (R3's (256,5)=102 cap was
// the suspected spill trigger); actual use ~90 -> 5 waves/SIMD.
__global__ __launch_bounds__(256, 4) void pscn_main(
    const int*   __restrict__ recep,
    const float* __restrict__ nf,
    const short8* __restrict__ bfrag,
    const float* __restrict__ b1,
    const float* __restrict__ w2,
    const float* __restrict__ cb2,
    const float* __restrict__ fcw,
    float*       __restrict__ out)
{
    __shared__ float cred[3][32][33];   // K-split partials, conflict-free (stride 33)
    __shared__ float y1s[32][33];       // [c1][pos]
    __shared__ float w2s[1024];         // w2s[c1*32+c2]
    __shared__ float contrib[32];

    const int tid  = threadIdx.x;
    const int lane = tid & 63;
    const int wv   = __builtin_amdgcn_readfirstlane(tid >> 6);
    const int ks   = wv;                // K-split id 0..3
    const int m    = lane & 31;         // position (MFMA A: m=lane&31)
    const int half = lane >> 5;         // k-half   (MFMA A: k=half*8+j)

    for (int i = tid; i < 1024; i += 256) {
        int c1 = i >> 5, c2 = i & 31;
        w2s[c1 * 32 + c2] = w2[c2 * 32 + c1];
    }

    const int sid = blockIdx.x * 32 + m;
    const int b   = sid / SEQ;
    const int sp  = sid - b * SEQ;

    const int* rr = recep + b * NN + sp * NB;
    const int idxA = rr[2 * ks];
    const int idxB = rr[2 * ks + 1];
    const int idxC = rr[8 + (ks >> 1)];

    const float* rp[3];
    rp[0] = nf + ((size_t)b * NN + idxA) * DD + half * 8;
    rp[1] = nf + ((size_t)b * NN + idxB) * DD + half * 8;
    rp[2] = nf + ((size_t)b * NN + idxC) * DD + (ks & 1) * 64 + half * 8;

    f32x16 C;
#pragma unroll
    for (int i = 0; i < 16; ++i) C[i] = 0.f;

    const short8* bp = bfrag + ks * 20 * 64 + lane;

    // software pipeline: 20 single-MFMA steps, prefetch depth 3, 4 rotating slots
    float4 Ab[4][2];
    short8 Bb[4];
#pragma unroll
    for (int t = 0; t < 3; ++t) {
        const float* p = rp[t >> 3] + (t & 7) * 16;
        Ab[t][0] = ((const float4*)p)[0];
        Ab[t][1] = ((const float4*)p)[1];
        Bb[t]    = bp[t * 64];
    }
#pragma unroll
    for (int t = 0; t < 20; ++t) {
        if (t + 3 < 20) {
            const int tn = t + 3;                 // compile-time after unroll
            const int sl = tn & 3;
            const float* p = rp[tn >> 3] + (tn & 7) * 16;
            Ab[sl][0] = ((const float4*)p)[0];
            Ab[sl][1] = ((const float4*)p)[1];
            Bb[sl]    = bp[tn * 64];
        }
        const int sc = t & 3;
        short8 a = cvt8(Ab[sc][0], Ab[sc][1]);
        C = __builtin_amdgcn_mfma_f32_32x32x16_bf16(a, Bb[sc], C, 0, 0, 0);
    }

    // reduce K-split partials; C/D: col(c1)=lane&31, row(p)=(r&3)+8*(r>>2)+4*half
    if (ks > 0) {
#pragma unroll
        for (int r = 0; r < 16; ++r) {
            int p = (r & 3) + 8 * (r >> 2) + 4 * half;
            cred[ks - 1][p][m] = C[r];
        }
    }
    __syncthreads();
    if (ks == 0) {
        float bv = b1[m];
#pragma unroll
        for (int r = 0; r < 16; ++r) {
            int p = (r & 3) + 8 * (r >> 2) + 4 * half;
            float v = C[r] + cred[0][p][m] + cred[1][p][m] + cred[2][p][m] + bv;
            y1s[m][p] = fmaxf(v, 0.f);
        }
    }
    __syncthreads();

    // conv2 (1x1) + relu + fc partial: thread = (s_l = tid>>3, oc = tid&7), 4 c2 each
    {
        const int s_l  = tid >> 3;
        const int oc   = tid & 7;
        const int sid2 = blockIdx.x * 32 + s_l;
        const int bb   = sid2 / SEQ;
        const int sp2  = sid2 - bb * SEQ;
        float val = 0.f;
#pragma unroll
        for (int j = 0; j < 4; ++j) {
            const int c2 = oc * 4 + j;
            float y2 = cb2[c2];
#pragma unroll
            for (int c1 = 0; c1 < 32; ++c1)
                y2 += y1s[c1][s_l] * w2s[c1 * 32 + c2];
            y2 = fmaxf(y2, 0.f);
            val += y2 * fcw[c2 * SEQ + sp2];
        }
        val += __shfl_xor(val, 1);
        val += __shfl_xor(val, 2);
        val += __shfl_xor(val, 4);
        if (oc == 0) contrib[s_l] = val;
    }
    __syncthreads();

    // block reduce (<=2 distinct graphs per 32-pos block) + atomicAdd
    if (wv == 0) {
        float v = (lane < 32) ? contrib[lane] : 0.f;
        const int bl     = (blockIdx.x * 32 + (lane & 31)) / SEQ;
        const int bfirst = (blockIdx.x * 32) / SEQ;
        const int blast  = (blockIdx.x * 32 + 31) / SEQ;
        for (int tb = bfirst; tb <= blast; ++tb) {
            float r = (bl == tb && lane < 32) ? v : 0.f;
#pragma unroll
            for (int off = 1; off < 64; off <<= 1) r += __shfl_xor(r, off);
            if (lane == 0) atomicAdd(&out[tb], r);
        }
    }
}

extern "C" void kernel_launch(void* const* d_in, const int* in_sizes, int n_in,
                              void* d_out, int out_size, void* d_ws, size_t ws_size,
                              hipStream_t stream) {
    const int*   recep = (const int*)  d_in[0];
    const float* nfeat = (const float*)d_in[1];
    const float* w1    = (const float*)d_in[2];
    const float* b1    = (const float*)d_in[3];
    const float* w2    = (const float*)d_in[4];
    const float* cb2   = (const float*)d_in[5];
    const float* fcw   = (const float*)d_in[6];
    const float* fcb   = (const float*)d_in[7];
    float* outp = (float*)d_out;
    unsigned short* bfrag = (unsigned short*)d_ws;   // 40960 bf16 = 80 KB

    pscn_prep<<<160, 256, 0, stream>>>(w1, bfrag);
    pscn_init_out<<<1, 128, 0, stream>>>(fcb, outp);
    pscn_main<<<(BSZ * SEQ) / 32, 256, 0, stream>>>(
        recep, nfeat, (const short8*)d_ws, b1, w2, cb2, fcw, outp);
}